// Round 10
// baseline (7034.622 us; speedup 1.0000x reference)
//
#include <hip/hip_runtime.h>

#define BATCH 8
#define NPTS  2048
#define KNN   20
#define NEG_INF_F (-3.402823466e38f)
#define NEG_INF_D (-1.7976931348623157e308)

__device__ __forceinline__ float fmul_(float a, float b){ return __fmul_rn(a,b); }
__device__ __forceinline__ float fadd_(float a, float b){ return __fadd_rn(a,b); }
__device__ __forceinline__ float fsub_(float a, float b){ return __fsub_rn(a,b); }

// ---------------- transpose input [B,3,N] -> x0 f32 [B*N,4] (pad) ----------------
__global__ void k_transpose_in(const float* __restrict__ x, float* __restrict__ o) {
    int i = blockIdx.x * blockDim.x + threadIdx.x;
    if (i >= BATCH * 3 * NPTS) return;
    int b = i / (3 * NPTS); int r = i % (3 * NPTS); int c = r / NPTS; int n = r % NPTS;
    size_t row = (size_t)b * NPTS + n;
    o[row * 4 + c] = x[i];
    if (c == 0) o[row * 4 + 3] = 0.f;
}

// ---------------- xx[b,n] = sum_c x^2, np-faithful f32 (FROZEN) ----------------
__global__ void k_sumsq(const float* __restrict__ X, int ldx, int coff, int C,
                        float* __restrict__ xx) {
    int i = blockIdx.x * blockDim.x + threadIdx.x;
    if (i >= BATCH * NPTS) return;
    const float* p = X + (size_t)i * ldx + coff;
    float s = 0.f;
    for (int c = 0; c < C; ++c) s = fadd_(s, fmul_(p[c], p[c]));
    xx[i] = s;
}

// ---------------- pd (per batch): np-faithful f32 sequential-c, no FMA (FROZEN) ----------------
__global__ __launch_bounds__(256) void k_pd(const float* __restrict__ Xb, int ldx, int coff, int C,
                                            const float* __restrict__ xxb, float* __restrict__ pd) {
    __shared__ float An[64][17];
    __shared__ float Am[64][17];
    int tx = threadIdx.x, ty = threadIdx.y, tid = ty * 16 + tx;
    int lrow = tid >> 2, lc4 = (tid & 3) << 2;
    int nB = blockIdx.y * 64, mB = blockIdx.x * 64;
    float acc[4][4] = {};
    for (int k0 = 0; k0 < C; k0 += 16) {
        #pragma unroll
        for (int j = 0; j < 4; ++j) {
            int kc = k0 + lc4 + j;
            An[lrow][lc4+j] = (kc < C) ? Xb[(size_t)(nB + lrow) * ldx + coff + kc] : 0.f;
            Am[lrow][lc4+j] = (kc < C) ? Xb[(size_t)(mB + lrow) * ldx + coff + kc] : 0.f;
        }
        __syncthreads();
        #pragma unroll
        for (int kk = 0; kk < 16; ++kk) {
            float a[4], w[4];
            #pragma unroll
            for (int i = 0; i < 4; ++i) a[i] = An[ty*4+i][kk];
            #pragma unroll
            for (int j = 0; j < 4; ++j) w[j] = Am[tx*4+j][kk];
            #pragma unroll
            for (int i = 0; i < 4; ++i)
                #pragma unroll
                for (int j = 0; j < 4; ++j)
                    acc[i][j] = fadd_(acc[i][j], fmul_(a[i], w[j]));   // sequential c, no FMA
        }
        __syncthreads();
    }
    #pragma unroll
    for (int i = 0; i < 4; ++i) {
        int n = nB + ty*4 + i;
        float xn = xxb[n];
        #pragma unroll
        for (int j = 0; j < 4; ++j) {
            int m = mB + tx*4 + j;
            pd[(size_t)n * NPTS + m] = fsub_(fsub_(fmul_(2.0f, acc[i][j]), xn), xxb[m]);
        }
    }
}

// ---------------- top-20 per pd row: register-cached shfl argmax (exact order-equivalent) ----------------
// Selection semantics identical to the old LDS-scan version: max value, lowest index on tie.
// Max-with-min-index is associative+commutative, so the butterfly reduce order is immaterial.
__global__ __launch_bounds__(256) void k_topk(const float* __restrict__ pd, int gbase,
                                              int* __restrict__ idx) {
    __shared__ float wv_[4];
    __shared__ int   wi_[4];
    __shared__ int   gi_;
    int r = blockIdx.x, tid = threadIdx.x;
    const float* src = pd + (size_t)r * NPTS;
    float v[8];
    #pragma unroll
    for (int j = 0; j < 8; ++j) v[j] = src[tid + j * 256];   // coalesced; m = tid + j*256
    // cached local best (ascending j scan, strict > keeps lowest m within thread)
    float lv = v[0]; int lj = 0;
    #pragma unroll
    for (int j = 1; j < 8; ++j) if (v[j] > lv) { lv = v[j]; lj = j; }
    int lane = tid & 63, wid = tid >> 6;
    for (int it = 0; it < KNN; ++it) {
        float bv = lv; int bm = tid + lj * 256;
        #pragma unroll
        for (int d = 32; d > 0; d >>= 1) {
            float ov = __shfl_xor(bv, d, 64);
            int   om = __shfl_xor(bm, d, 64);
            if (ov > bv || (ov == bv && om < bm)) { bv = ov; bm = om; }
        }
        if (lane == 0) { wv_[wid] = bv; wi_[wid] = bm; }
        __syncthreads();
        if (tid == 0) {
            float gv = wv_[0]; int gm = wi_[0];
            #pragma unroll
            for (int k = 1; k < 4; ++k) {
                float ov = wv_[k]; int om = wi_[k];
                if (ov > gv || (ov == gv && om < gm)) { gv = ov; gm = om; }
            }
            gi_ = gm;
            idx[(size_t)(gbase + r) * KNN + it] = gm;
        }
        __syncthreads();
        int gm = gi_;
        if ((gm & 255) == tid) {            // owner: remove slot and refresh cached best
            v[gm >> 8] = NEG_INF_F;
            lv = v[0]; lj = 0;
            #pragma unroll
            for (int j = 1; j < 8; ++j) if (v[j] > lv) { lv = v[j]; lj = j; }
        }
    }
}

// ---------------- faithful edge conv (layers 1-3): ROUND-7 VERBATIM (FROZEN) ----------------
#define CCHUNK 16
__global__ void k_edge_conv(const float* __restrict__ X, int ldx, int coff, int C, int O,
                            const float* __restrict__ w, const int* __restrict__ idx,
                            float* __restrict__ ymax, double* __restrict__ part) {
    __shared__ float sc[128];
    __shared__ int   si[KNN];
    __shared__ float sn[KNN * 128];
    __shared__ float wt[256 * (CCHUNK + 1)];
    int o = threadIdx.x;
    int blk = blockIdx.x;
    int C2 = 2 * C;
    double s1 = 0.0, s2 = 0.0;
    for (int jn = 0; jn < 8; ++jn) {
        int n = blk * 8 + jn;
        int b = n >> 11, nl = n & 2047;
        const float* Xb = X + ((size_t)b * NPTS) * ldx + coff;
        for (int t = o; t < C; t += O) sc[t] = Xb[(size_t)nl * ldx + t];
        if (o < KNN) si[o] = idx[(size_t)n * KNN + o];
        __syncthreads();
        for (int t = o; t < KNN * C; t += O) sn[t] = Xb[(size_t)si[t / C] * ldx + (t % C)];
        __syncthreads();
        float acc[KNN];
        #pragma unroll
        for (int k = 0; k < KNN; ++k) acc[k] = 0.f;
        for (int c0 = 0; c0 < C2; c0 += CCHUNK) {
            for (int t = o; t < O * CCHUNK; t += O) {
                int oo = t / CCHUNK, c2 = t % CCHUNK; int c = c0 + c2;
                wt[oo * (CCHUNK + 1) + c2] = (c < C2) ? w[(size_t)oo * C2 + c] : 0.f;
            }
            __syncthreads();
            int cend = (C2 - c0 < CCHUNK) ? (C2 - c0) : CCHUNK;
            for (int c2 = 0; c2 < cend; ++c2) {
                int c = c0 + c2;
                float wv = wt[o * (CCHUNK + 1) + c2];
                if (c < C) {
                    float cv = sc[c];
                    #pragma unroll
                    for (int k = 0; k < KNN; ++k)
                        acc[k] = fadd_(acc[k], fmul_(wv, fsub_(sn[k * C + c], cv)));
                } else {
                    float fv = sc[c - C];
                    #pragma unroll
                    for (int k = 0; k < KNN; ++k)
                        acc[k] = fadd_(acc[k], fmul_(wv, fv));
                }
            }
            __syncthreads();
        }
        float mx = acc[0];
        #pragma unroll
        for (int k = 1; k < KNN; ++k) mx = fmaxf(mx, acc[k]);
        ymax[(size_t)n * O + o] = mx;
        #pragma unroll
        for (int k = 0; k < KNN; ++k) { double v = (double)acc[k]; s1 += v; s2 += v * v; }
        __syncthreads();
    }
    part[(size_t)blk * (2 * O) + o]     = s1;
    part[(size_t)blk * (2 * O) + O + o] = s2;
}

// ---------------- BN stats: serial (1 block, O threads) — FROZEN ----------------
__global__ void k_bn_stats(const double* __restrict__ part, int nparts, int O,
                           float* __restrict__ mst, float* __restrict__ vst) {
    int o = threadIdx.x;
    double s1 = 0.0, s2 = 0.0;
    for (int p = 0; p < nparts; ++p) { s1 += part[(size_t)p * 2 * O + o]; s2 += part[(size_t)p * 2 * O + O + o]; }
    const double cnt = (double)BATCH * NPTS * KNN;
    double m = s1 / cnt;
    double v = s2 / cnt - m * m; if (v < 0.0) v = 0.0;
    mst[o] = (float)m; vst[o] = (float)v;
}

// ---------------- BN apply + lrelu, np-faithful f32 op sequence (FROZEN) ----------------
__global__ void k_bn_apply(const float* __restrict__ ymax, int O,
                           const float* __restrict__ mst, const float* __restrict__ vst,
                           const float* __restrict__ g, const float* __restrict__ bb,
                           float* __restrict__ loc, int coff) {
    int i = blockIdx.x * blockDim.x + threadIdx.x;   // M*O
    int m = i / O, o = i % O;
    float r = __fdiv_rn(1.0f, __fsqrt_rn(fadd_(vst[o], 1e-5f)));
    float t = fsub_(ymax[i], mst[o]);
    t = fmul_(t, r);
    t = fmul_(t, g[o]);
    t = fadd_(t, bb[o]);
    if (t < 0.f) t = fmul_(0.2f, t);
    loc[(size_t)m * 512 + coff + o] = t;
}

// ---------------- weight prep (block 4): w[O,2C] -> w2[2O,C] (z-rows | u-rows) ----------------
__global__ void k_wprep(const float* __restrict__ w, int C, int O, float* __restrict__ w2) {
    int i = blockIdx.x * blockDim.x + threadIdx.x;
    if (i >= 2 * O * C) return;
    int o = i / C, c = i % C;
    if (o < O) w2[i] = w[(size_t)o * 2 * C + c];
    else { int oo = o - O; w2[i] = w[(size_t)oo * 2 * C + C + c] - w[(size_t)oo * 2 * C + c]; }
}

// ---------------- big GEMM (value path): 128x128 tile, 8x8/thread, f32 FMA ----------------
__global__ __launch_bounds__(256) void k_gemm_big(const float* __restrict__ A, int lda, int aoff,
                                                  const float* __restrict__ W, int ldw,
                                                  float* __restrict__ out, int ldo, int Kdim,
                                                  const float* __restrict__ bias,
                                                  const double* __restrict__ bvec, int OB) {
    __shared__ float As[128][17];
    __shared__ float Ws[128][17];
    int tx = threadIdx.x, ty = threadIdx.y;
    int tid = ty * 16 + tx;
    int lrow = tid >> 1, kc = (tid & 1) * 8;
    int m0 = blockIdx.y * 128, o0 = blockIdx.x * 128;
    float acc[8][8] = {};
    for (int k0 = 0; k0 < Kdim; k0 += 16) {
        const float* pa = A + (size_t)(m0 + lrow) * lda + aoff + k0 + kc;
        const float* pw = W + (size_t)(o0 + lrow) * ldw + k0 + kc;
        float4 a0 = *(const float4*)pa;
        float4 a1 = *(const float4*)(pa + 4);
        float4 w0 = *(const float4*)pw;
        float4 w1 = *(const float4*)(pw + 4);
        As[lrow][kc+0]=a0.x; As[lrow][kc+1]=a0.y; As[lrow][kc+2]=a0.z; As[lrow][kc+3]=a0.w;
        As[lrow][kc+4]=a1.x; As[lrow][kc+5]=a1.y; As[lrow][kc+6]=a1.z; As[lrow][kc+7]=a1.w;
        Ws[lrow][kc+0]=w0.x; Ws[lrow][kc+1]=w0.y; Ws[lrow][kc+2]=w0.z; Ws[lrow][kc+3]=w0.w;
        Ws[lrow][kc+4]=w1.x; Ws[lrow][kc+5]=w1.y; Ws[lrow][kc+6]=w1.z; Ws[lrow][kc+7]=w1.w;
        __syncthreads();
        #pragma unroll
        for (int kk = 0; kk < 16; ++kk) {
            float a[8], w[8];
            #pragma unroll
            for (int i = 0; i < 8; ++i) a[i] = As[ty*8+i][kk];
            #pragma unroll
            for (int j = 0; j < 8; ++j) w[j] = Ws[tx*8+j][kk];
            #pragma unroll
            for (int i = 0; i < 8; ++i)
                #pragma unroll
                for (int j = 0; j < 8; ++j) acc[i][j] = fmaf(a[i], w[j], acc[i][j]);
        }
        __syncthreads();
    }
    #pragma unroll
    for (int i = 0; i < 8; ++i) {
        int m = m0 + ty*8 + i;
        const double* bv = bvec ? (bvec + (size_t)(m >> 11) * OB) : nullptr;
        #pragma unroll
        for (int j = 0; j < 8; ++j) {
            int o = o0 + tx*8 + j;
            float v = acc[i][j];
            if (bias) v += bias[o];
            if (bv)   v += (float)bv[o];
            out[(size_t)m * ldo + o] = v;
        }
    }
}

// ---------------- block-4 gather reduce (per batch): max + stats from zu ----------------
__global__ void k_edge_reduce4(const float* __restrict__ zu, const int* __restrict__ idxb,
                               float* __restrict__ ymaxb, double* __restrict__ partb) {
    __shared__ int sidx[16 * KNN];
    int o = threadIdx.x;            // 256
    int tile = blockIdx.x;          // 128
    int n0 = tile * 16;
    for (int t = o; t < 16 * KNN; t += 256)
        sidx[t] = idxb[(size_t)(n0 + t / KNN) * KNN + (t % KNN)];
    __syncthreads();
    double s1 = 0.0, s2 = 0.0;
    for (int nn = 0; nn < 16; ++nn) {
        int n = n0 + nn;
        float u = zu[(size_t)n * 512 + 256 + o];
        float mx = NEG_INF_F; double sz = 0.0, sq = 0.0;
        #pragma unroll
        for (int k = 0; k < KNN; ++k) {
            float zv = zu[(size_t)sidx[nn * KNN + k] * 512 + o];
            mx = fmaxf(mx, zv);
            double y = (double)zv + (double)u;
            sz += (double)zv; sq += y * y;
        }
        ymaxb[(size_t)n * 256 + o] = mx + u;
        s1 += sz + (double)KNN * (double)u;
        s2 += sq;
    }
    partb[(size_t)tile * 512 + o]       = s1;
    partb[(size_t)tile * 512 + 256 + o] = s2;
}

// ---------------- GroupNorm stats per (b,group), f64 ----------------
__global__ void k_gn_stats(const float* __restrict__ h, int C, int cg, double* __restrict__ gst) {
    __shared__ double ss[256], sq[256];
    int blk = blockIdx.x;           // b*32 + grp
    int b = blk >> 5, grp = blk & 31;
    int tid = threadIdx.x;
    int tot = NPTS * cg;
    double s = 0.0, q = 0.0;
    for (int e = tid; e < tot; e += 256) {
        int n = e / cg, ci = e % cg;
        double v = (double)h[((size_t)b * NPTS + n) * C + grp * cg + ci];
        s += v; q += v * v;
    }
    ss[tid] = s; sq[tid] = q;
    __syncthreads();
    for (int st = 128; st > 0; st >>= 1) {
        if (tid < st) { ss[tid] += ss[tid + st]; sq[tid] += sq[tid + st]; }
        __syncthreads();
    }
    if (tid == 0) {
        double cnt = (double)tot;
        double mean = ss[0] / cnt;
        double var = fmax(sq[0] / cnt - mean * mean, 0.0);
        gst[blk * 2]     = mean;
        gst[blk * 2 + 1] = rsqrt(var + 1e-5);
    }
}

// ---------------- GroupNorm apply (+relu/lrelu), in place ----------------
__global__ void k_gn_apply(float* __restrict__ h, int C, int cg, const double* __restrict__ gst,
                           const float* __restrict__ g, const float* __restrict__ bb, int act) {
    int i = blockIdx.x * blockDim.x + threadIdx.x;   // M*C
    int m = i / C, c = i % C;
    int b = m >> 11, grp = c / cg;
    double mean = gst[(b * 32 + grp) * 2], inv = gst[(b * 32 + grp) * 2 + 1];
    double v = ((double)h[i] - mean) * inv * (double)g[c] + (double)bb[c];
    v = act ? fmax(v, 0.0) : ((v >= 0.0) ? v : 0.2 * v);
    h[i] = (float)v;
}

// ---------------- final GN + relu + transpose to [B,128,N] ----------------
__global__ void k_gn_out(const float* __restrict__ h, const double* __restrict__ gst,
                         const float* __restrict__ g, const float* __restrict__ bb,
                         float* __restrict__ out) {
    int i = blockIdx.x * blockDim.x + threadIdx.x;   // B*128*N
    int b = i / (128 * NPTS); int r = i % (128 * NPTS); int c = r / NPTS; int n = r % NPTS;
    int grp = c >> 2;
    double mean = gst[(b * 32 + grp) * 2], inv = gst[(b * 32 + grp) * 2 + 1];
    double v = ((double)h[((size_t)b * NPTS + n) * 128 + c] - mean) * inv * (double)g[c] + (double)bb[c];
    out[i] = (float)fmax(v, 0.0);
}

// ---------------- global pooling: grid (16, 8), 256 thr ----------------
__global__ void k_glb(const float* __restrict__ h, double* __restrict__ glb) {
    __shared__ double smx[256], ssm[256];
    int b  = blockIdx.y;
    int c  = blockIdx.x * 32 + (threadIdx.x & 31);
    int g  = threadIdx.x >> 5;
    const float* hb = h + (size_t)b * NPTS * 512;
    double mx = NEG_INF_D, s = 0.0;
    for (int n = g; n < NPTS; n += 8) {
        double v = (double)hb[(size_t)n * 512 + c];
        mx = fmax(mx, v); s += v;
    }
    smx[threadIdx.x] = mx; ssm[threadIdx.x] = s;
    __syncthreads();
    for (int st = 128; st >= 32; st >>= 1) {
        if (threadIdx.x < st) {
            smx[threadIdx.x] = fmax(smx[threadIdx.x], smx[threadIdx.x + st]);
            ssm[threadIdx.x] += ssm[threadIdx.x + st];
        }
        __syncthreads();
    }
    if (threadIdx.x < 32) {
        glb[b * 1024 + c]       = smx[threadIdx.x];
        glb[b * 1024 + 512 + c] = ssm[threadIdx.x] * (1.0 / NPTS);
    }
}

// ---------------- v[b,o] = bm1[o] + glb[b,:] . wm1[o,512:1536] ----------------
__global__ void k_vvec(const double* __restrict__ glb, const float* __restrict__ wm1,
                       const float* __restrict__ bm1, double* __restrict__ v) {
    int b = blockIdx.x; int o = threadIdx.x;
    const double* gb = glb + b * 1024;
    const float*  wr = wm1 + (size_t)o * 1536 + 512;
    double s = (double)bm1[o];
    for (int c = 0; c < 1024; ++c) s += gb[c] * (double)wr[c];
    v[b * 512 + o] = s;
}

// =================================================================================
extern "C" void kernel_launch(void* const* d_in, const int* in_sizes, int n_in,
                              void* d_out, int out_size, void* d_ws, size_t ws_size,
                              hipStream_t stream) {
    const float* xyz = (const float*)d_in[0];
    const float* w1 = (const float*)d_in[1];  const float* g1 = (const float*)d_in[2];  const float* b1 = (const float*)d_in[3];
    const float* w2 = (const float*)d_in[4];  const float* g2 = (const float*)d_in[5];  const float* b2 = (const float*)d_in[6];
    const float* w3 = (const float*)d_in[7];  const float* g3 = (const float*)d_in[8];  const float* b3 = (const float*)d_in[9];
    const float* w4 = (const float*)d_in[10]; const float* g4 = (const float*)d_in[11]; const float* b4 = (const float*)d_in[12];
    const float* w5 = (const float*)d_in[13]; const float* g5 = (const float*)d_in[14]; const float* b5 = (const float*)d_in[15];
    const float* wm1 = (const float*)d_in[16]; const float* bm1 = (const float*)d_in[17];
    const float* g6 = (const float*)d_in[18]; const float* b6 = (const float*)d_in[19];
    const float* wm2 = (const float*)d_in[20]; const float* bm2 = (const float*)d_in[21];
    const float* g7 = (const float*)d_in[22]; const float* b7 = (const float*)d_in[23];
    const float* wm3 = (const float*)d_in[24]; const float* bm3 = (const float*)d_in[25];
    const float* g8 = (const float*)d_in[26]; const float* b8 = (const float*)d_in[27];

    char* ws = (char*)d_ws;
    const size_t MiB = 1024ull * 1024;
    const size_t oLoc  = 0;                      // loc f32 [16384,512] 32 MiB
    const size_t oU    = 32 * MiB;               // union region (48 MiB)
    const size_t oPd   = oU;                     //   pd f32 [2048,2048] 16 MiB       (knn)
    const size_t oPart = oU + 16 * MiB;          //   part f64 <=4 MiB                (conv)
    const size_t oYmax = oU + 20 * MiB;          //   ymax f32 [16384,<=256] 16 MiB   (conv)
    const size_t oZu   = oU + 36 * MiB;          //   zu_b f32 [2048,512] 4 MiB       (conv4)
    const size_t oH5   = oU;                     //   h5/h6/h8 f32 [16384,512] 32 MiB (dense)
    const size_t oH7   = oU + 32 * MiB;          //   h7 f32 [16384,256] 16 MiB       (dense)
    const size_t oX0   = 80 * MiB;               // x0 f32 [16384,4]
    const size_t oXX   = oX0 + 256 * 1024;       // xx f32 [16384]
    const size_t oIdx  = oXX + 64 * 1024;        // idx [16384,20] int
    const size_t oMst  = oIdx + 1344 * 1024;
    const size_t oVst  = oMst + 1024;
    const size_t oGst  = oVst + 1024;            // gst f64 [512]
    const size_t oGlb  = oGst + 4096;            // glb f64 [8,1024]
    const size_t oVv   = oGlb + 65536;           // vv f64 [8,512]
    const size_t oW2   = oVv + 32768;            // w2p f32 [512,128]

    float*  loc  = (float*)(ws + oLoc);
    float*  pd   = (float*)(ws + oPd);
    double* part = (double*)(ws + oPart);
    float*  ymax = (float*)(ws + oYmax);
    float*  zu   = (float*)(ws + oZu);
    float*  h5   = (float*)(ws + oH5);
    float*  h7   = (float*)(ws + oH7);
    float*  x0   = (float*)(ws + oX0);
    float*  xx   = (float*)(ws + oXX);
    int*    idx  = (int*)  (ws + oIdx);
    float*  mst  = (float*)(ws + oMst);
    float*  vst  = (float*)(ws + oVst);
    double* gst  = (double*)(ws + oGst);
    double* glb  = (double*)(ws + oGlb);
    double* vv   = (double*)(ws + oVv);
    float*  w2p  = (float*)(ws + oW2);

    dim3 t16(16, 16);
    const int M = BATCH * NPTS;   // 16384

    k_transpose_in<<<(BATCH*3*NPTS + 255)/256, 256, 0, stream>>>(xyz, x0);

    // ---- layers 1-3: faithful knn + ROUND-7 frozen conv/stats ----
    struct EB { int isX0; int ldx; int coff; int C; int O; const float* w; const float* g; const float* bb; int coff_out; };
    EB eb[3] = {
        { 1, 4,   0,  3,  64,  w1, g1, b1, 0   },
        { 0, 512, 0,  64, 64,  w2, g2, b2, 64  },
        { 0, 512, 64, 64, 128, w3, g3, b3, 128 },
    };
    for (int e = 0; e < 3; ++e) {
        const EB& p = eb[e];
        const float* X = p.isX0 ? x0 : loc;
        k_sumsq<<<M/256, 256, 0, stream>>>(X, p.ldx, p.coff, p.C, xx);
        for (int b = 0; b < BATCH; ++b) {
            k_pd<<<dim3(NPTS/64, NPTS/64), t16, 0, stream>>>(X + (size_t)b*NPTS*p.ldx, p.ldx, p.coff, p.C,
                                                             xx + (size_t)b*NPTS, pd);
            k_topk<<<NPTS, 256, 0, stream>>>(pd, b * NPTS, idx);
        }
        k_edge_conv<<<M/8, p.O, 0, stream>>>(X, p.ldx, p.coff, p.C, p.O, p.w, idx, ymax, part);
        k_bn_stats<<<1, p.O, 0, stream>>>(part, M/8, p.O, mst, vst);
        k_bn_apply<<<(M*p.O)/256, 256, 0, stream>>>(ymax, p.O, mst, vst, p.g, p.bb, loc, p.coff_out);
    }

    // ---- layer 4: faithful knn + factored conv (value path, no downstream knn) ----
    k_sumsq<<<M/256, 256, 0, stream>>>(loc, 512, 128, 128, xx);
    for (int b = 0; b < BATCH; ++b) {
        k_pd<<<dim3(NPTS/64, NPTS/64), t16, 0, stream>>>(loc + (size_t)b*NPTS*512, 512, 128, 128,
                                                         xx + (size_t)b*NPTS, pd);
        k_topk<<<NPTS, 256, 0, stream>>>(pd, b * NPTS, idx);
    }
    k_wprep<<<(512*128 + 255)/256, 256, 0, stream>>>(w4, 128, 256, w2p);
    for (int b = 0; b < BATCH; ++b) {
        k_gemm_big<<<dim3(512/128, NPTS/128), t16, 0, stream>>>(loc + (size_t)b*NPTS*512, 512, 128,
                                                                w2p, 128, zu, 512, 128,
                                                                nullptr, nullptr, 0);
        k_edge_reduce4<<<128, 256, 0, stream>>>(zu, idx + (size_t)b*NPTS*KNN,
                                                ymax + (size_t)b*NPTS*256,
                                                part + (size_t)b*128*512);
    }
    k_bn_stats<<<1, 256, 0, stream>>>(part, BATCH*128, 256, mst, vst);
    k_bn_apply<<<(M*256)/256, 256, 0, stream>>>(ymax, 256, mst, vst, g4, b4, loc, 256);

    // ---- dense phase ----
    float* h6 = h5;              // h5 dead after glb
    float* h8 = h5;              // h6 dead after wm2

    k_gemm_big<<<dim3(512/128, M/128), t16, 0, stream>>>(loc, 512, 0, w5, 512, h5, 512, 512, nullptr, nullptr, 0);
    k_gn_stats<<<BATCH*32, 256, 0, stream>>>(h5, 512, 16, gst);
    k_gn_apply<<<(M*512)/256, 256, 0, stream>>>(h5, 512, 16, gst, g5, b5, 0);

    k_glb<<<dim3(16, 8), 256, 0, stream>>>(h5, glb);
    k_vvec<<<BATCH, 512, 0, stream>>>(glb, wm1, bm1, vv);

    k_gemm_big<<<dim3(512/128, M/128), t16, 0, stream>>>(loc, 512, 0, wm1, 1536, h6, 512, 512, nullptr, vv, 512);
    k_gn_stats<<<BATCH*32, 256, 0, stream>>>(h6, 512, 16, gst);
    k_gn_apply<<<(M*512)/256, 256, 0, stream>>>(h6, 512, 16, gst, g6, b6, 1);

    k_gemm_big<<<dim3(256/128, M/128), t16, 0, stream>>>(h6, 512, 0, wm2, 512, h7, 256, 512, bm2, nullptr, 0);
    k_gn_stats<<<BATCH*32, 256, 0, stream>>>(h7, 256, 8, gst);
    k_gn_apply<<<(M*256)/256, 256, 0, stream>>>(h7, 256, 8, gst, g7, b7, 1);

    k_gemm_big<<<dim3(128/128, M/128), t16, 0, stream>>>(h7, 256, 0, wm3, 256, h8, 128, 256, bm3, nullptr, 0);
    k_gn_stats<<<BATCH*32, 256, 0, stream>>>(h8, 128, 4, gst);
    k_gn_out<<<(BATCH*128*NPTS)/256, 256, 0, stream>>>(h8, gst, g8, b8, (float*)d_out);
}

// Round 11
// 6544.583 us; speedup vs baseline: 1.0749x; 1.0749x over previous
//
#include <hip/hip_runtime.h>

#define BATCH 8
#define NPTS  2048
#define KNN   20
#define NEG_INF_F (-3.402823466e38f)
#define NEG_INF_D (-1.7976931348623157e308)

__device__ __forceinline__ float fmul_(float a, float b){ return __fmul_rn(a,b); }
__device__ __forceinline__ float fadd_(float a, float b){ return __fadd_rn(a,b); }
__device__ __forceinline__ float fsub_(float a, float b){ return __fsub_rn(a,b); }

// ---------------- transpose input [B,3,N] -> x0 f32 [B*N,4] (pad) ----------------
__global__ void k_transpose_in(const float* __restrict__ x, float* __restrict__ o) {
    int i = blockIdx.x * blockDim.x + threadIdx.x;
    if (i >= BATCH * 3 * NPTS) return;
    int b = i / (3 * NPTS); int r = i % (3 * NPTS); int c = r / NPTS; int n = r % NPTS;
    size_t row = (size_t)b * NPTS + n;
    o[row * 4 + c] = x[i];
    if (c == 0) o[row * 4 + 3] = 0.f;
}

// ---------------- xx[b,n] = sum_c x^2, np-faithful f32 (FROZEN) ----------------
__global__ void k_sumsq(const float* __restrict__ X, int ldx, int coff, int C,
                        float* __restrict__ xx) {
    int i = blockIdx.x * blockDim.x + threadIdx.x;
    if (i >= BATCH * NPTS) return;
    const float* p = X + (size_t)i * ldx + coff;
    float s = 0.f;
    for (int c = 0; c < C; ++c) s = fadd_(s, fmul_(p[c], p[c]));
    xx[i] = s;
}

// ---------------- pd (per batch): np-faithful f32 sequential-c, no FMA (FROZEN) ----------------
__global__ __launch_bounds__(256) void k_pd(const float* __restrict__ Xb, int ldx, int coff, int C,
                                            const float* __restrict__ xxb, float* __restrict__ pd) {
    __shared__ float An[64][17];
    __shared__ float Am[64][17];
    int tx = threadIdx.x, ty = threadIdx.y, tid = ty * 16 + tx;
    int lrow = tid >> 2, lc4 = (tid & 3) << 2;
    int nB = blockIdx.y * 64, mB = blockIdx.x * 64;
    float acc[4][4] = {};
    for (int k0 = 0; k0 < C; k0 += 16) {
        #pragma unroll
        for (int j = 0; j < 4; ++j) {
            int kc = k0 + lc4 + j;
            An[lrow][lc4+j] = (kc < C) ? Xb[(size_t)(nB + lrow) * ldx + coff + kc] : 0.f;
            Am[lrow][lc4+j] = (kc < C) ? Xb[(size_t)(mB + lrow) * ldx + coff + kc] : 0.f;
        }
        __syncthreads();
        #pragma unroll
        for (int kk = 0; kk < 16; ++kk) {
            float a[4], w[4];
            #pragma unroll
            for (int i = 0; i < 4; ++i) a[i] = An[ty*4+i][kk];
            #pragma unroll
            for (int j = 0; j < 4; ++j) w[j] = Am[tx*4+j][kk];
            #pragma unroll
            for (int i = 0; i < 4; ++i)
                #pragma unroll
                for (int j = 0; j < 4; ++j)
                    acc[i][j] = fadd_(acc[i][j], fmul_(a[i], w[j]));   // sequential c, no FMA
        }
        __syncthreads();
    }
    #pragma unroll
    for (int i = 0; i < 4; ++i) {
        int n = nB + ty*4 + i;
        float xn = xxb[n];
        #pragma unroll
        for (int j = 0; j < 4; ++j) {
            int m = mB + tx*4 + j;
            pd[(size_t)n * NPTS + m] = fsub_(fsub_(fmul_(2.0f, acc[i][j]), xn), xxb[m]);
        }
    }
}

// ---------------- top-20 per pd row: register-cached shfl argmax (exact, verified r10) ----------------
__global__ __launch_bounds__(256) void k_topk(const float* __restrict__ pd, int gbase,
                                              int* __restrict__ idx) {
    __shared__ float wv_[4];
    __shared__ int   wi_[4];
    __shared__ int   gi_;
    int r = blockIdx.x, tid = threadIdx.x;
    const float* src = pd + (size_t)r * NPTS;
    float v[8];
    #pragma unroll
    for (int j = 0; j < 8; ++j) v[j] = src[tid + j * 256];   // coalesced; m = tid + j*256
    float lv = v[0]; int lj = 0;
    #pragma unroll
    for (int j = 1; j < 8; ++j) if (v[j] > lv) { lv = v[j]; lj = j; }
    int lane = tid & 63, wid = tid >> 6;
    for (int it = 0; it < KNN; ++it) {
        float bv = lv; int bm = tid + lj * 256;
        #pragma unroll
        for (int d = 32; d > 0; d >>= 1) {
            float ov = __shfl_xor(bv, d, 64);
            int   om = __shfl_xor(bm, d, 64);
            if (ov > bv || (ov == bv && om < bm)) { bv = ov; bm = om; }
        }
        if (lane == 0) { wv_[wid] = bv; wi_[wid] = bm; }
        __syncthreads();
        if (tid == 0) {
            float gv = wv_[0]; int gm = wi_[0];
            #pragma unroll
            for (int k = 1; k < 4; ++k) {
                float ov = wv_[k]; int om = wi_[k];
                if (ov > gv || (ov == gv && om < gm)) { gv = ov; gm = om; }
            }
            gi_ = gm;
            idx[(size_t)(gbase + r) * KNN + it] = gm;
        }
        __syncthreads();
        int gm = gi_;
        if ((gm & 255) == tid) {
            v[gm >> 8] = NEG_INF_F;
            lv = v[0]; lj = 0;
            #pragma unroll
            for (int j = 1; j < 8; ++j) if (v[j] > lv) { lv = v[j]; lj = j; }
        }
    }
}

// ---------------- faithful edge conv (layers 1-3): ROUND-7 VERBATIM (FROZEN) ----------------
#define CCHUNK 16
__global__ void k_edge_conv(const float* __restrict__ X, int ldx, int coff, int C, int O,
                            const float* __restrict__ w, const int* __restrict__ idx,
                            float* __restrict__ ymax, double* __restrict__ part) {
    __shared__ float sc[128];
    __shared__ int   si[KNN];
    __shared__ float sn[KNN * 128];
    __shared__ float wt[256 * (CCHUNK + 1)];
    int o = threadIdx.x;
    int blk = blockIdx.x;
    int C2 = 2 * C;
    double s1 = 0.0, s2 = 0.0;
    for (int jn = 0; jn < 8; ++jn) {
        int n = blk * 8 + jn;
        int b = n >> 11, nl = n & 2047;
        const float* Xb = X + ((size_t)b * NPTS) * ldx + coff;
        for (int t = o; t < C; t += O) sc[t] = Xb[(size_t)nl * ldx + t];
        if (o < KNN) si[o] = idx[(size_t)n * KNN + o];
        __syncthreads();
        for (int t = o; t < KNN * C; t += O) sn[t] = Xb[(size_t)si[t / C] * ldx + (t % C)];
        __syncthreads();
        float acc[KNN];
        #pragma unroll
        for (int k = 0; k < KNN; ++k) acc[k] = 0.f;
        for (int c0 = 0; c0 < C2; c0 += CCHUNK) {
            for (int t = o; t < O * CCHUNK; t += O) {
                int oo = t / CCHUNK, c2 = t % CCHUNK; int c = c0 + c2;
                wt[oo * (CCHUNK + 1) + c2] = (c < C2) ? w[(size_t)oo * C2 + c] : 0.f;
            }
            __syncthreads();
            int cend = (C2 - c0 < CCHUNK) ? (C2 - c0) : CCHUNK;
            for (int c2 = 0; c2 < cend; ++c2) {
                int c = c0 + c2;
                float wv = wt[o * (CCHUNK + 1) + c2];
                if (c < C) {
                    float cv = sc[c];
                    #pragma unroll
                    for (int k = 0; k < KNN; ++k)
                        acc[k] = fadd_(acc[k], fmul_(wv, fsub_(sn[k * C + c], cv)));
                } else {
                    float fv = sc[c - C];
                    #pragma unroll
                    for (int k = 0; k < KNN; ++k)
                        acc[k] = fadd_(acc[k], fmul_(wv, fv));
                }
            }
            __syncthreads();
        }
        float mx = acc[0];
        #pragma unroll
        for (int k = 1; k < KNN; ++k) mx = fmaxf(mx, acc[k]);
        ymax[(size_t)n * O + o] = mx;
        #pragma unroll
        for (int k = 0; k < KNN; ++k) { double v = (double)acc[k]; s1 += v; s2 += v * v; }
        __syncthreads();
    }
    part[(size_t)blk * (2 * O) + o]     = s1;
    part[(size_t)blk * (2 * O) + O + o] = s2;
}

// ---------------- BN stats L1-3: serial (1 block, O threads) — FROZEN ----------------
__global__ void k_bn_stats(const double* __restrict__ part, int nparts, int O,
                           float* __restrict__ mst, float* __restrict__ vst) {
    int o = threadIdx.x;
    double s1 = 0.0, s2 = 0.0;
    for (int p = 0; p < nparts; ++p) { s1 += part[(size_t)p * 2 * O + o]; s2 += part[(size_t)p * 2 * O + O + o]; }
    const double cnt = (double)BATCH * NPTS * KNN;
    double m = s1 / cnt;
    double v = s2 / cnt - m * m; if (v < 0.0) v = 0.0;
    mst[o] = (float)m; vst[o] = (float)v;
}

// ---------------- BN stats L4: parallel tree (value path — L4 feeds dense only) ----------------
__global__ __launch_bounds__(256) void k_bn_stats4(const double* __restrict__ part, int nparts,
                                                   float* __restrict__ mst, float* __restrict__ vst) {
    __shared__ double r1[256], r2[256];
    int o = blockIdx.x, tid = threadIdx.x;       // grid 256 (O=256), 2O stride = 512
    double s1 = 0.0, s2 = 0.0;
    for (int p = tid; p < nparts; p += 256) {
        s1 += part[(size_t)p * 512 + o];
        s2 += part[(size_t)p * 512 + 256 + o];
    }
    r1[tid] = s1; r2[tid] = s2;
    __syncthreads();
    for (int s = 128; s > 0; s >>= 1) {
        if (tid < s) { r1[tid] += r1[tid + s]; r2[tid] += r2[tid + s]; }
        __syncthreads();
    }
    if (tid == 0) {
        const double cnt = (double)BATCH * NPTS * KNN;
        double m = r1[0] / cnt;
        double v = r2[0] / cnt - m * m; if (v < 0.0) v = 0.0;
        mst[o] = (float)m; vst[o] = (float)v;
    }
}

// ---------------- BN apply + lrelu, np-faithful f32 op sequence (FROZEN) ----------------
__global__ void k_bn_apply(const float* __restrict__ ymax, int O,
                           const float* __restrict__ mst, const float* __restrict__ vst,
                           const float* __restrict__ g, const float* __restrict__ bb,
                           float* __restrict__ loc, int coff) {
    int i = blockIdx.x * blockDim.x + threadIdx.x;   // M*O
    int m = i / O, o = i % O;
    float r = __fdiv_rn(1.0f, __fsqrt_rn(fadd_(vst[o], 1e-5f)));
    float t = fsub_(ymax[i], mst[o]);
    t = fmul_(t, r);
    t = fmul_(t, g[o]);
    t = fadd_(t, bb[o]);
    if (t < 0.f) t = fmul_(0.2f, t);
    loc[(size_t)m * 512 + coff + o] = t;
}

// ---------------- weight prep (block 4): w[O,2C] -> w2[2O,C] (z-rows | u-rows) ----------------
__global__ void k_wprep(const float* __restrict__ w, int C, int O, float* __restrict__ w2) {
    int i = blockIdx.x * blockDim.x + threadIdx.x;
    if (i >= 2 * O * C) return;
    int o = i / C, c = i % C;
    if (o < O) w2[i] = w[(size_t)o * 2 * C + c];
    else { int oo = o - O; w2[i] = w[(size_t)oo * 2 * C + C + c] - w[(size_t)oo * 2 * C + c]; }
}

// ---------------- big GEMM (value path): 128x128 tile, 8x8/thread, f32 FMA; optional z-batch ----------------
__global__ __launch_bounds__(256) void k_gemm_big(const float* __restrict__ A, int lda, int aoff,
                                                  const float* __restrict__ W, int ldw,
                                                  float* __restrict__ out, int ldo, int Kdim,
                                                  const float* __restrict__ bias,
                                                  const double* __restrict__ bvec, int OB,
                                                  size_t zstrA, size_t zstrO) {
    A   += (size_t)blockIdx.z * zstrA;
    out += (size_t)blockIdx.z * zstrO;
    __shared__ float As[128][17];
    __shared__ float Ws[128][17];
    int tx = threadIdx.x, ty = threadIdx.y;
    int tid = ty * 16 + tx;
    int lrow = tid >> 1, kc = (tid & 1) * 8;
    int m0 = blockIdx.y * 128, o0 = blockIdx.x * 128;
    float acc[8][8] = {};
    for (int k0 = 0; k0 < Kdim; k0 += 16) {
        const float* pa = A + (size_t)(m0 + lrow) * lda + aoff + k0 + kc;
        const float* pw = W + (size_t)(o0 + lrow) * ldw + k0 + kc;
        float4 a0 = *(const float4*)pa;
        float4 a1 = *(const float4*)(pa + 4);
        float4 w0 = *(const float4*)pw;
        float4 w1 = *(const float4*)(pw + 4);
        As[lrow][kc+0]=a0.x; As[lrow][kc+1]=a0.y; As[lrow][kc+2]=a0.z; As[lrow][kc+3]=a0.w;
        As[lrow][kc+4]=a1.x; As[lrow][kc+5]=a1.y; As[lrow][kc+6]=a1.z; As[lrow][kc+7]=a1.w;
        Ws[lrow][kc+0]=w0.x; Ws[lrow][kc+1]=w0.y; Ws[lrow][kc+2]=w0.z; Ws[lrow][kc+3]=w0.w;
        Ws[lrow][kc+4]=w1.x; Ws[lrow][kc+5]=w1.y; Ws[lrow][kc+6]=w1.z; Ws[lrow][kc+7]=w1.w;
        __syncthreads();
        #pragma unroll
        for (int kk = 0; kk < 16; ++kk) {
            float a[8], w[8];
            #pragma unroll
            for (int i = 0; i < 8; ++i) a[i] = As[ty*8+i][kk];
            #pragma unroll
            for (int j = 0; j < 8; ++j) w[j] = Ws[tx*8+j][kk];
            #pragma unroll
            for (int i = 0; i < 8; ++i)
                #pragma unroll
                for (int j = 0; j < 8; ++j) acc[i][j] = fmaf(a[i], w[j], acc[i][j]);
        }
        __syncthreads();
    }
    #pragma unroll
    for (int i = 0; i < 8; ++i) {
        int m = m0 + ty*8 + i;
        const double* bv = bvec ? (bvec + (size_t)(m >> 11) * OB) : nullptr;
        #pragma unroll
        for (int j = 0; j < 8; ++j) {
            int o = o0 + tx*8 + j;
            float v = acc[i][j];
            if (bias) v += bias[o];
            if (bv)   v += (float)bv[o];
            out[(size_t)m * ldo + o] = v;
        }
    }
}

// ---------------- block-4 gather reduce, z-batched: max + stats from zu4 ----------------
__global__ void k_edge_reduce4(const float* __restrict__ zu4, const int* __restrict__ idx,
                               float* __restrict__ ymax, double* __restrict__ part, int b0) {
    __shared__ int sidx[16 * KNN];
    int o = threadIdx.x;            // 256
    int tile = blockIdx.x;          // 128
    int z = blockIdx.y;             // half-batch index
    const float* zu    = zu4  + (size_t)z * NPTS * 512;
    const int*   idxb  = idx  + (size_t)(b0 + z) * NPTS * KNN;
    float*       ymaxb = ymax + (size_t)(b0 + z) * NPTS * 256;
    double*      partb = part + (size_t)(b0 + z) * 128 * 512;
    int n0 = tile * 16;
    for (int t = o; t < 16 * KNN; t += 256)
        sidx[t] = idxb[(size_t)(n0 + t / KNN) * KNN + (t % KNN)];
    __syncthreads();
    double s1 = 0.0, s2 = 0.0;
    for (int nn = 0; nn < 16; ++nn) {
        int n = n0 + nn;
        float u = zu[(size_t)n * 512 + 256 + o];
        float mx = NEG_INF_F; double sz = 0.0, sq = 0.0;
        #pragma unroll
        for (int k = 0; k < KNN; ++k) {
            float zv = zu[(size_t)sidx[nn * KNN + k] * 512 + o];
            mx = fmaxf(mx, zv);
            double y = (double)zv + (double)u;
            sz += (double)zv; sq += y * y;
        }
        ymaxb[(size_t)n * 256 + o] = mx + u;
        s1 += sz + (double)KNN * (double)u;
        s2 += sq;
    }
    partb[(size_t)tile * 512 + o]       = s1;
    partb[(size_t)tile * 512 + 256 + o] = s2;
}

// ---------------- GroupNorm stats per (b,group), f64 ----------------
__global__ void k_gn_stats(const float* __restrict__ h, int C, int cg, double* __restrict__ gst) {
    __shared__ double ss[256], sq[256];
    int blk = blockIdx.x;           // b*32 + grp
    int b = blk >> 5, grp = blk & 31;
    int tid = threadIdx.x;
    int tot = NPTS * cg;
    double s = 0.0, q = 0.0;
    for (int e = tid; e < tot; e += 256) {
        int n = e / cg, ci = e % cg;
        double v = (double)h[((size_t)b * NPTS + n) * C + grp * cg + ci];
        s += v; q += v * v;
    }
    ss[tid] = s; sq[tid] = q;
    __syncthreads();
    for (int st = 128; st > 0; st >>= 1) {
        if (tid < st) { ss[tid] += ss[tid + st]; sq[tid] += sq[tid + st]; }
        __syncthreads();
    }
    if (tid == 0) {
        double cnt = (double)tot;
        double mean = ss[0] / cnt;
        double var = fmax(sq[0] / cnt - mean * mean, 0.0);
        gst[blk * 2]     = mean;
        gst[blk * 2 + 1] = rsqrt(var + 1e-5);
    }
}

// ---------------- GroupNorm apply (+relu/lrelu), in place ----------------
__global__ void k_gn_apply(float* __restrict__ h, int C, int cg, const double* __restrict__ gst,
                           const float* __restrict__ g, const float* __restrict__ bb, int act) {
    int i = blockIdx.x * blockDim.x + threadIdx.x;   // M*C
    int m = i / C, c = i % C;
    int b = m >> 11, grp = c / cg;
    double mean = gst[(b * 32 + grp) * 2], inv = gst[(b * 32 + grp) * 2 + 1];
    double v = ((double)h[i] - mean) * inv * (double)g[c] + (double)bb[c];
    v = act ? fmax(v, 0.0) : ((v >= 0.0) ? v : 0.2 * v);
    h[i] = (float)v;
}

// ---------------- final GN + relu + transpose to [B,128,N] ----------------
__global__ void k_gn_out(const float* __restrict__ h, const double* __restrict__ gst,
                         const float* __restrict__ g, const float* __restrict__ bb,
                         float* __restrict__ out) {
    int i = blockIdx.x * blockDim.x + threadIdx.x;   // B*128*N
    int b = i / (128 * NPTS); int r = i % (128 * NPTS); int c = r / NPTS; int n = r % NPTS;
    int grp = c >> 2;
    double mean = gst[(b * 32 + grp) * 2], inv = gst[(b * 32 + grp) * 2 + 1];
    double v = ((double)h[((size_t)b * NPTS + n) * 128 + c] - mean) * inv * (double)g[c] + (double)bb[c];
    out[i] = (float)fmax(v, 0.0);
}

// ---------------- global pooling: grid (16, 8), 256 thr ----------------
__global__ void k_glb(const float* __restrict__ h, double* __restrict__ glb) {
    __shared__ double smx[256], ssm[256];
    int b  = blockIdx.y;
    int c  = blockIdx.x * 32 + (threadIdx.x & 31);
    int g  = threadIdx.x >> 5;
    const float* hb = h + (size_t)b * NPTS * 512;
    double mx = NEG_INF_D, s = 0.0;
    for (int n = g; n < NPTS; n += 8) {
        double v = (double)hb[(size_t)n * 512 + c];
        mx = fmax(mx, v); s += v;
    }
    smx[threadIdx.x] = mx; ssm[threadIdx.x] = s;
    __syncthreads();
    for (int st = 128; st >= 32; st >>= 1) {
        if (threadIdx.x < st) {
            smx[threadIdx.x] = fmax(smx[threadIdx.x], smx[threadIdx.x + st]);
            ssm[threadIdx.x] += ssm[threadIdx.x + st];
        }
        __syncthreads();
    }
    if (threadIdx.x < 32) {
        glb[b * 1024 + c]       = smx[threadIdx.x];
        glb[b * 1024 + 512 + c] = ssm[threadIdx.x] * (1.0 / NPTS);
    }
}

// ---------------- v[b,o] = bm1[o] + glb[b,:] . wm1[o,512:1536] ----------------
__global__ void k_vvec(const double* __restrict__ glb, const float* __restrict__ wm1,
                       const float* __restrict__ bm1, double* __restrict__ v) {
    int b = blockIdx.x; int o = threadIdx.x;
    const double* gb = glb + b * 1024;
    const float*  wr = wm1 + (size_t)o * 1536 + 512;
    double s = (double)bm1[o];
    for (int c = 0; c < 1024; ++c) s += gb[c] * (double)wr[c];
    v[b * 512 + o] = s;
}

// =================================================================================
extern "C" void kernel_launch(void* const* d_in, const int* in_sizes, int n_in,
                              void* d_out, int out_size, void* d_ws, size_t ws_size,
                              hipStream_t stream) {
    const float* xyz = (const float*)d_in[0];
    const float* w1 = (const float*)d_in[1];  const float* g1 = (const float*)d_in[2];  const float* b1 = (const float*)d_in[3];
    const float* w2 = (const float*)d_in[4];  const float* g2 = (const float*)d_in[5];  const float* b2 = (const float*)d_in[6];
    const float* w3 = (const float*)d_in[7];  const float* g3 = (const float*)d_in[8];  const float* b3 = (const float*)d_in[9];
    const float* w4 = (const float*)d_in[10]; const float* g4 = (const float*)d_in[11]; const float* b4 = (const float*)d_in[12];
    const float* w5 = (const float*)d_in[13]; const float* g5 = (const float*)d_in[14]; const float* b5 = (const float*)d_in[15];
    const float* wm1 = (const float*)d_in[16]; const float* bm1 = (const float*)d_in[17];
    const float* g6 = (const float*)d_in[18]; const float* b6 = (const float*)d_in[19];
    const float* wm2 = (const float*)d_in[20]; const float* bm2 = (const float*)d_in[21];
    const float* g7 = (const float*)d_in[22]; const float* b7 = (const float*)d_in[23];
    const float* wm3 = (const float*)d_in[24]; const float* bm3 = (const float*)d_in[25];
    const float* g8 = (const float*)d_in[26]; const float* b8 = (const float*)d_in[27];

    char* ws = (char*)d_ws;
    const size_t MiB = 1024ull * 1024;
    const size_t oLoc  = 0;                      // loc f32 [16384,512] 32 MiB
    const size_t oU    = 32 * MiB;               // union region (48 MiB)
    const size_t oPd   = oU;                     //   pd f32 [2048,2048] 16 MiB       (knn)
    const size_t oZu4  = oU;                     //   zu4 f32 [4][2048,512] 16 MiB    (conv4; pd dead)
    const size_t oPart = oU + 16 * MiB;          //   part f64 <=4 MiB                (conv)
    const size_t oYmax = oU + 20 * MiB;          //   ymax f32 [16384,<=256] 16 MiB   (conv)
    const size_t oH5   = oU;                     //   h5/h6/h8 f32 [16384,512] 32 MiB (dense)
    const size_t oH7   = oU + 32 * MiB;          //   h7 f32 [16384,256] 16 MiB       (dense)
    const size_t oX0   = 80 * MiB;               // x0 f32 [16384,4]
    const size_t oXX   = oX0 + 256 * 1024;       // xx f32 [16384]
    const size_t oIdx  = oXX + 64 * 1024;        // idx [16384,20] int
    const size_t oMst  = oIdx + 1344 * 1024;
    const size_t oVst  = oMst + 1024;
    const size_t oGst  = oVst + 1024;            // gst f64 [512]
    const size_t oGlb  = oGst + 4096;            // glb f64 [8,1024]
    const size_t oVv   = oGlb + 65536;           // vv f64 [8,512]
    const size_t oW2   = oVv + 32768;            // w2p f32 [512,128]

    float*  loc  = (float*)(ws + oLoc);
    float*  pd   = (float*)(ws + oPd);
    float*  zu4  = (float*)(ws + oZu4);
    double* part = (double*)(ws + oPart);
    float*  ymax = (float*)(ws + oYmax);
    float*  h5   = (float*)(ws + oH5);
    float*  h7   = (float*)(ws + oH7);
    float*  x0   = (float*)(ws + oX0);
    float*  xx   = (float*)(ws + oXX);
    int*    idx  = (int*)  (ws + oIdx);
    float*  mst  = (float*)(ws + oMst);
    float*  vst  = (float*)(ws + oVst);
    double* gst  = (double*)(ws + oGst);
    double* glb  = (double*)(ws + oGlb);
    double* vv   = (double*)(ws + oVv);
    float*  w2p  = (float*)(ws + oW2);

    dim3 t16(16, 16);
    const int M = BATCH * NPTS;   // 16384

    k_transpose_in<<<(BATCH*3*NPTS + 255)/256, 256, 0, stream>>>(xyz, x0);

    // ---- layers 1-3: faithful knn + ROUND-7 frozen conv/stats ----
    struct EB { int isX0; int ldx; int coff; int C; int O; const float* w; const float* g; const float* bb; int coff_out; };
    EB eb[3] = {
        { 1, 4,   0,  3,  64,  w1, g1, b1, 0   },
        { 0, 512, 0,  64, 64,  w2, g2, b2, 64  },
        { 0, 512, 64, 64, 128, w3, g3, b3, 128 },
    };
    for (int e = 0; e < 3; ++e) {
        const EB& p = eb[e];
        const float* X = p.isX0 ? x0 : loc;
        k_sumsq<<<M/256, 256, 0, stream>>>(X, p.ldx, p.coff, p.C, xx);
        for (int b = 0; b < BATCH; ++b) {
            k_pd<<<dim3(NPTS/64, NPTS/64), t16, 0, stream>>>(X + (size_t)b*NPTS*p.ldx, p.ldx, p.coff, p.C,
                                                             xx + (size_t)b*NPTS, pd);
            k_topk<<<NPTS, 256, 0, stream>>>(pd, b * NPTS, idx);
        }
        k_edge_conv<<<M/8, p.O, 0, stream>>>(X, p.ldx, p.coff, p.C, p.O, p.w, idx, ymax, part);
        k_bn_stats<<<1, p.O, 0, stream>>>(part, M/8, p.O, mst, vst);
        k_bn_apply<<<(M*p.O)/256, 256, 0, stream>>>(ymax, p.O, mst, vst, p.g, p.bb, loc, p.coff_out);
    }

    // ---- layer 4: faithful knn + factored conv (value path), z-batched by half-batch ----
    k_sumsq<<<M/256, 256, 0, stream>>>(loc, 512, 128, 128, xx);
    for (int b = 0; b < BATCH; ++b) {
        k_pd<<<dim3(NPTS/64, NPTS/64), t16, 0, stream>>>(loc + (size_t)b*NPTS*512, 512, 128, 128,
                                                         xx + (size_t)b*NPTS, pd);
        k_topk<<<NPTS, 256, 0, stream>>>(pd, b * NPTS, idx);
    }
    // idx complete for all batches -> pd region dead -> zu4 may overwrite it
    k_wprep<<<(512*128 + 255)/256, 256, 0, stream>>>(w4, 128, 256, w2p);
    for (int hb = 0; hb < 2; ++hb) {
        int b0 = hb * 4;
        k_gemm_big<<<dim3(512/128, NPTS/128, 4), t16, 0, stream>>>(
            loc + (size_t)b0*NPTS*512, 512, 128, w2p, 128, zu4, 512, 128,
            nullptr, nullptr, 0, (size_t)NPTS*512, (size_t)NPTS*512);
        k_edge_reduce4<<<dim3(128, 4), 256, 0, stream>>>(zu4, idx, ymax, part, b0);
    }
    k_bn_stats4<<<256, 256, 0, stream>>>(part, BATCH*128, mst, vst);
    k_bn_apply<<<(M*256)/256, 256, 0, stream>>>(ymax, 256, mst, vst, g4, b4, loc, 256);

    // ---- dense phase ----
    float* h6 = h5;              // h5 dead after glb
    float* h8 = h5;              // h6 dead after wm2

    k_gemm_big<<<dim3(512/128, M/128), t16, 0, stream>>>(loc, 512, 0, w5, 512, h5, 512, 512,
                                                         nullptr, nullptr, 0, 0, 0);
    k_gn_stats<<<BATCH*32, 256, 0, stream>>>(h5, 512, 16, gst);
    k_gn_apply<<<(M*512)/256, 256, 0, stream>>>(h5, 512, 16, gst, g5, b5, 0);

    k_glb<<<dim3(16, 8), 256, 0, stream>>>(h5, glb);
    k_vvec<<<BATCH, 512, 0, stream>>>(glb, wm1, bm1, vv);

    k_gemm_big<<<dim3(512/128, M/128), t16, 0, stream>>>(loc, 512, 0, wm1, 1536, h6, 512, 512,
                                                         nullptr, vv, 512, 0, 0);
    k_gn_stats<<<BATCH*32, 256, 0, stream>>>(h6, 512, 16, gst);
    k_gn_apply<<<(M*512)/256, 256, 0, stream>>>(h6, 512, 16, gst, g6, b6, 1);

    k_gemm_big<<<dim3(256/128, M/128), t16, 0, stream>>>(h6, 512, 0, wm2, 512, h7, 256, 512,
                                                         bm2, nullptr, 0, 0, 0);
    k_gn_stats<<<BATCH*32, 256, 0, stream>>>(h7, 256, 8, gst);
    k_gn_apply<<<(M*256)/256, 256, 0, stream>>>(h7, 256, 8, gst, g7, b7, 1);

    k_gemm_big<<<dim3(128/128, M/128), t16, 0, stream>>>(h7, 256, 0, wm3, 256, h8, 128, 256,
                                                         bm3, nullptr, 0, 0, 0);
    k_gn_stats<<<BATCH*32, 256, 0, stream>>>(h8, 128, 4, gst);
    k_gn_out<<<(BATCH*128*NPTS)/256, 256, 0, stream>>>(h8, gst, g8, b8, (float*)d_out);
}

// Round 12
// 6101.234 us; speedup vs baseline: 1.1530x; 1.0727x over previous
//
#include <hip/hip_runtime.h>

#define BATCH 8
#define NPTS  2048
#define KNN   20
#define NEG_INF_F (-3.402823466e38f)
#define NEG_INF_D (-1.7976931348623157e308)

__device__ __forceinline__ float fmul_(float a, float b){ return __fmul_rn(a,b); }
__device__ __forceinline__ float fadd_(float a, float b){ return __fadd_rn(a,b); }
__device__ __forceinline__ float fsub_(float a, float b){ return __fsub_rn(a,b); }

// ---------------- transpose input [B,3,N] -> x0 f32 [B*N,4] (pad) ----------------
__global__ void k_transpose_in(const float* __restrict__ x, float* __restrict__ o) {
    int i = blockIdx.x * blockDim.x + threadIdx.x;
    if (i >= BATCH * 3 * NPTS) return;
    int b = i / (3 * NPTS); int r = i % (3 * NPTS); int c = r / NPTS; int n = r % NPTS;
    size_t row = (size_t)b * NPTS + n;
    o[row * 4 + c] = x[i];
    if (c == 0) o[row * 4 + 3] = 0.f;
}

// ---------------- xx[b,n] = sum_c x^2, np-faithful f32 (FROZEN) ----------------
__global__ void k_sumsq(const float* __restrict__ X, int ldx, int coff, int C,
                        float* __restrict__ xx) {
    int i = blockIdx.x * blockDim.x + threadIdx.x;
    if (i >= BATCH * NPTS) return;
    const float* p = X + (size_t)i * ldx + coff;
    float s = 0.f;
    for (int c = 0; c < C; ++c) s = fadd_(s, fmul_(p[c], p[c]));
    xx[i] = s;
}

// ---------------- pd (per batch): np-faithful f32 sequential-c, no FMA (FROZEN) ----------------
__global__ __launch_bounds__(256) void k_pd(const float* __restrict__ Xb, int ldx, int coff, int C,
                                            const float* __restrict__ xxb, float* __restrict__ pd) {
    __shared__ float An[64][17];
    __shared__ float Am[64][17];
    int tx = threadIdx.x, ty = threadIdx.y, tid = ty * 16 + tx;
    int lrow = tid >> 2, lc4 = (tid & 3) << 2;
    int nB = blockIdx.y * 64, mB = blockIdx.x * 64;
    float acc[4][4] = {};
    for (int k0 = 0; k0 < C; k0 += 16) {
        #pragma unroll
        for (int j = 0; j < 4; ++j) {
            int kc = k0 + lc4 + j;
            An[lrow][lc4+j] = (kc < C) ? Xb[(size_t)(nB + lrow) * ldx + coff + kc] : 0.f;
            Am[lrow][lc4+j] = (kc < C) ? Xb[(size_t)(mB + lrow) * ldx + coff + kc] : 0.f;
        }
        __syncthreads();
        #pragma unroll
        for (int kk = 0; kk < 16; ++kk) {
            float a[4], w[4];
            #pragma unroll
            for (int i = 0; i < 4; ++i) a[i] = An[ty*4+i][kk];
            #pragma unroll
            for (int j = 0; j < 4; ++j) w[j] = Am[tx*4+j][kk];
            #pragma unroll
            for (int i = 0; i < 4; ++i)
                #pragma unroll
                for (int j = 0; j < 4; ++j)
                    acc[i][j] = fadd_(acc[i][j], fmul_(a[i], w[j]));   // sequential c, no FMA
        }
        __syncthreads();
    }
    #pragma unroll
    for (int i = 0; i < 4; ++i) {
        int n = nB + ty*4 + i;
        float xn = xxb[n];
        #pragma unroll
        for (int j = 0; j < 4; ++j) {
            int m = mB + tx*4 + j;
            pd[(size_t)n * NPTS + m] = fsub_(fsub_(fmul_(2.0f, acc[i][j]), xn), xxb[m]);
        }
    }
}

// ---------------- top-20: wave-per-row, register-cached, barrier-free (exact order-equivalent) ----------------
// Same total order as verified r10 kernel: max value, lowest index on tie. Butterfly reduce over
// 64 lanes of the associative/commutative (max,min-idx) operator == sequential scan result.
__global__ __launch_bounds__(256) void k_topk(const float* __restrict__ pd, int gbase,
                                              int* __restrict__ idx) {
    int wid = threadIdx.x >> 6, lane = threadIdx.x & 63;
    int r = blockIdx.x * 4 + wid;
    const float* src = pd + (size_t)r * NPTS;
    float v[32];
    #pragma unroll
    for (int j = 0; j < 32; ++j) v[j] = src[lane + j * 64];   // m = lane + j*64, coalesced
    // lane-local best: ascending j == ascending m -> strict > keeps lowest m
    float lv = v[0]; int lj = 0;
    #pragma unroll
    for (int j = 1; j < 32; ++j) if (v[j] > lv) { lv = v[j]; lj = j; }
    for (int it = 0; it < KNN; ++it) {
        float bv = lv; int bm = lane + lj * 64;
        #pragma unroll
        for (int d = 32; d > 0; d >>= 1) {
            float ov = __shfl_xor(bv, d, 64);
            int   om = __shfl_xor(bm, d, 64);
            if (ov > bv || (ov == bv && om < bm)) { bv = ov; bm = om; }
        }
        if (lane == 0) idx[(size_t)(gbase + r) * KNN + it] = bm;
        if ((bm & 63) == lane) {               // owner: knock out and refresh local best
            v[bm >> 6] = NEG_INF_F;
            lv = v[0]; lj = 0;
            #pragma unroll
            for (int j = 1; j < 32; ++j) if (v[j] > lv) { lv = v[j]; lj = j; }
        }
    }
}

// ---------------- faithful edge conv (layers 1-3): ROUND-7 VERBATIM (FROZEN) ----------------
#define CCHUNK 16
__global__ void k_edge_conv(const float* __restrict__ X, int ldx, int coff, int C, int O,
                            const float* __restrict__ w, const int* __restrict__ idx,
                            float* __restrict__ ymax, double* __restrict__ part) {
    __shared__ float sc[128];
    __shared__ int   si[KNN];
    __shared__ float sn[KNN * 128];
    __shared__ float wt[256 * (CCHUNK + 1)];
    int o = threadIdx.x;
    int blk = blockIdx.x;
    int C2 = 2 * C;
    double s1 = 0.0, s2 = 0.0;
    for (int jn = 0; jn < 8; ++jn) {
        int n = blk * 8 + jn;
        int b = n >> 11, nl = n & 2047;
        const float* Xb = X + ((size_t)b * NPTS) * ldx + coff;
        for (int t = o; t < C; t += O) sc[t] = Xb[(size_t)nl * ldx + t];
        if (o < KNN) si[o] = idx[(size_t)n * KNN + o];
        __syncthreads();
        for (int t = o; t < KNN * C; t += O) sn[t] = Xb[(size_t)si[t / C] * ldx + (t % C)];
        __syncthreads();
        float acc[KNN];
        #pragma unroll
        for (int k = 0; k < KNN; ++k) acc[k] = 0.f;
        for (int c0 = 0; c0 < C2; c0 += CCHUNK) {
            for (int t = o; t < O * CCHUNK; t += O) {
                int oo = t / CCHUNK, c2 = t % CCHUNK; int c = c0 + c2;
                wt[oo * (CCHUNK + 1) + c2] = (c < C2) ? w[(size_t)oo * C2 + c] : 0.f;
            }
            __syncthreads();
            int cend = (C2 - c0 < CCHUNK) ? (C2 - c0) : CCHUNK;
            for (int c2 = 0; c2 < cend; ++c2) {
                int c = c0 + c2;
                float wv = wt[o * (CCHUNK + 1) + c2];
                if (c < C) {
                    float cv = sc[c];
                    #pragma unroll
                    for (int k = 0; k < KNN; ++k)
                        acc[k] = fadd_(acc[k], fmul_(wv, fsub_(sn[k * C + c], cv)));
                } else {
                    float fv = sc[c - C];
                    #pragma unroll
                    for (int k = 0; k < KNN; ++k)
                        acc[k] = fadd_(acc[k], fmul_(wv, fv));
                }
            }
            __syncthreads();
        }
        float mx = acc[0];
        #pragma unroll
        for (int k = 1; k < KNN; ++k) mx = fmaxf(mx, acc[k]);
        ymax[(size_t)n * O + o] = mx;
        #pragma unroll
        for (int k = 0; k < KNN; ++k) { double v = (double)acc[k]; s1 += v; s2 += v * v; }
        __syncthreads();
    }
    part[(size_t)blk * (2 * O) + o]     = s1;
    part[(size_t)blk * (2 * O) + O + o] = s2;
}

// ---------------- BN stats L1-3: serial (1 block, O threads) — FROZEN ----------------
__global__ void k_bn_stats(const double* __restrict__ part, int nparts, int O,
                           float* __restrict__ mst, float* __restrict__ vst) {
    int o = threadIdx.x;
    double s1 = 0.0, s2 = 0.0;
    for (int p = 0; p < nparts; ++p) { s1 += part[(size_t)p * 2 * O + o]; s2 += part[(size_t)p * 2 * O + O + o]; }
    const double cnt = (double)BATCH * NPTS * KNN;
    double m = s1 / cnt;
    double v = s2 / cnt - m * m; if (v < 0.0) v = 0.0;
    mst[o] = (float)m; vst[o] = (float)v;
}

// ---------------- BN stats L4: parallel tree (value path — L4 feeds dense only) ----------------
__global__ __launch_bounds__(256) void k_bn_stats4(const double* __restrict__ part, int nparts,
                                                   float* __restrict__ mst, float* __restrict__ vst) {
    __shared__ double r1[256], r2[256];
    int o = blockIdx.x, tid = threadIdx.x;       // grid 256 (O=256), 2O stride = 512
    double s1 = 0.0, s2 = 0.0;
    for (int p = tid; p < nparts; p += 256) {
        s1 += part[(size_t)p * 512 + o];
        s2 += part[(size_t)p * 512 + 256 + o];
    }
    r1[tid] = s1; r2[tid] = s2;
    __syncthreads();
    for (int s = 128; s > 0; s >>= 1) {
        if (tid < s) { r1[tid] += r1[tid + s]; r2[tid] += r2[tid + s]; }
        __syncthreads();
    }
    if (tid == 0) {
        const double cnt = (double)BATCH * NPTS * KNN;
        double m = r1[0] / cnt;
        double v = r2[0] / cnt - m * m; if (v < 0.0) v = 0.0;
        mst[o] = (float)m; vst[o] = (float)v;
    }
}

// ---------------- BN apply + lrelu, np-faithful f32 op sequence (FROZEN) ----------------
__global__ void k_bn_apply(const float* __restrict__ ymax, int O,
                           const float* __restrict__ mst, const float* __restrict__ vst,
                           const float* __restrict__ g, const float* __restrict__ bb,
                           float* __restrict__ loc, int coff) {
    int i = blockIdx.x * blockDim.x + threadIdx.x;   // M*O
    int m = i / O, o = i % O;
    float r = __fdiv_rn(1.0f, __fsqrt_rn(fadd_(vst[o], 1e-5f)));
    float t = fsub_(ymax[i], mst[o]);
    t = fmul_(t, r);
    t = fmul_(t, g[o]);
    t = fadd_(t, bb[o]);
    if (t < 0.f) t = fmul_(0.2f, t);
    loc[(size_t)m * 512 + coff + o] = t;
}

// ---------------- weight prep (block 4): w[O,2C] -> w2[2O,C] (z-rows | u-rows) ----------------
__global__ void k_wprep(const float* __restrict__ w, int C, int O, float* __restrict__ w2) {
    int i = blockIdx.x * blockDim.x + threadIdx.x;
    if (i >= 2 * O * C) return;
    int o = i / C, c = i % C;
    if (o < O) w2[i] = w[(size_t)o * 2 * C + c];
    else { int oo = o - O; w2[i] = w[(size_t)oo * 2 * C + C + c] - w[(size_t)oo * 2 * C + c]; }
}

// ---------------- big GEMM (value path): 128x128 tile, transposed LDS for b128 reads ----------------
// Per-output fmaf k-order identical to r11's gemm_big (k0 by 16, kk 0..15) -> bit-identical output.
__global__ __launch_bounds__(256) void k_gemm_t(const float* __restrict__ A, int lda, int aoff,
                                                const float* __restrict__ W, int ldw,
                                                float* __restrict__ out, int ldo, int Kdim,
                                                const float* __restrict__ bias,
                                                const double* __restrict__ bvec, int OB,
                                                size_t zstrA, size_t zstrO) {
    A   += (size_t)blockIdx.z * zstrA;
    out += (size_t)blockIdx.z * zstrO;
    __shared__ __align__(16) float AsT[16][132];
    __shared__ __align__(16) float WsT[16][132];
    int tx = threadIdx.x, ty = threadIdx.y;
    int tid = ty * 16 + tx;
    int lrow = tid >> 1, kc = (tid & 1) * 8;
    int m0 = blockIdx.y * 128, o0 = blockIdx.x * 128;
    float acc[8][8] = {};
    for (int k0 = 0; k0 < Kdim; k0 += 16) {
        const float* pa = A + (size_t)(m0 + lrow) * lda + aoff + k0 + kc;
        const float* pw = W + (size_t)(o0 + lrow) * ldw + k0 + kc;
        float4 a0 = *(const float4*)pa;
        float4 a1 = *(const float4*)(pa + 4);
        float4 w0 = *(const float4*)pw;
        float4 w1 = *(const float4*)(pw + 4);
        AsT[kc+0][lrow]=a0.x; AsT[kc+1][lrow]=a0.y; AsT[kc+2][lrow]=a0.z; AsT[kc+3][lrow]=a0.w;
        AsT[kc+4][lrow]=a1.x; AsT[kc+5][lrow]=a1.y; AsT[kc+6][lrow]=a1.z; AsT[kc+7][lrow]=a1.w;
        WsT[kc+0][lrow]=w0.x; WsT[kc+1][lrow]=w0.y; WsT[kc+2][lrow]=w0.z; WsT[kc+3][lrow]=w0.w;
        WsT[kc+4][lrow]=w1.x; WsT[kc+5][lrow]=w1.y; WsT[kc+6][lrow]=w1.z; WsT[kc+7][lrow]=w1.w;
        __syncthreads();
        #pragma unroll
        for (int kk = 0; kk < 16; ++kk) {
            float4 aA = *(const float4*)&AsT[kk][ty*8];
            float4 aB = *(const float4*)&AsT[kk][ty*8+4];
            float4 wA = *(const float4*)&WsT[kk][tx*8];
            float4 wB = *(const float4*)&WsT[kk][tx*8+4];
            float a[8] = {aA.x,aA.y,aA.z,aA.w,aB.x,aB.y,aB.z,aB.w};
            float w[8] = {wA.x,wA.y,wA.z,wA.w,wB.x,wB.y,wB.z,wB.w};
            #pragma unroll
            for (int i = 0; i < 8; ++i)
                #pragma unroll
                for (int j = 0; j < 8; ++j) acc[i][j] = fmaf(a[i], w[j], acc[i][j]);
        }
        __syncthreads();
    }
    #pragma unroll
    for (int i = 0; i < 8; ++i) {
        int m = m0 + ty*8 + i;
        const double* bv = bvec ? (bvec + (size_t)(m >> 11) * OB) : nullptr;
        #pragma unroll
        for (int j = 0; j < 8; ++j) {
            int o = o0 + tx*8 + j;
            float v = acc[i][j];
            if (bias) v += bias[o];
            if (bv)   v += (float)bv[o];
            out[(size_t)m * ldo + o] = v;
        }
    }
}

// ---------------- block-4 gather reduce, z-batched: max + stats from zu4 ----------------
__global__ void k_edge_reduce4(const float* __restrict__ zu4, const int* __restrict__ idx,
                               float* __restrict__ ymax, double* __restrict__ part, int b0) {
    __shared__ int sidx[16 * KNN];
    int o = threadIdx.x;            // 256
    int tile = blockIdx.x;          // 128
    int z = blockIdx.y;             // half-batch index
    const float* zu    = zu4  + (size_t)z * NPTS * 512;
    const int*   idxb  = idx  + (size_t)(b0 + z) * NPTS * KNN;
    float*       ymaxb = ymax + (size_t)(b0 + z) * NPTS * 256;
    double*      partb = part + (size_t)(b0 + z) * 128 * 512;
    int n0 = tile * 16;
    for (int t = o; t < 16 * KNN; t += 256)
        sidx[t] = idxb[(size_t)(n0 + t / KNN) * KNN + (t % KNN)];
    __syncthreads();
    double s1 = 0.0, s2 = 0.0;
    for (int nn = 0; nn < 16; ++nn) {
        int n = n0 + nn;
        float u = zu[(size_t)n * 512 + 256 + o];
        float mx = NEG_INF_F; double sz = 0.0, sq = 0.0;
        #pragma unroll
        for (int k = 0; k < KNN; ++k) {
            float zv = zu[(size_t)sidx[nn * KNN + k] * 512 + o];
            mx = fmaxf(mx, zv);
            double y = (double)zv + (double)u;
            sz += (double)zv; sq += y * y;
        }
        ymaxb[(size_t)n * 256 + o] = mx + u;
        s1 += sz + (double)KNN * (double)u;
        s2 += sq;
    }
    partb[(size_t)tile * 512 + o]       = s1;
    partb[(size_t)tile * 512 + 256 + o] = s2;
}

// ---------------- GroupNorm stats per (b,group), f64 ----------------
__global__ void k_gn_stats(const float* __restrict__ h, int C, int cg, double* __restrict__ gst) {
    __shared__ double ss[256], sq[256];
    int blk = blockIdx.x;           // b*32 + grp
    int b = blk >> 5, grp = blk & 31;
    int tid = threadIdx.x;
    int tot = NPTS * cg;
    double s = 0.0, q = 0.0;
    for (int e = tid; e < tot; e += 256) {
        int n = e / cg, ci = e % cg;
        double v = (double)h[((size_t)b * NPTS + n) * C + grp * cg + ci];
        s += v; q += v * v;
    }
    ss[tid] = s; sq[tid] = q;
    __syncthreads();
    for (int st = 128; st > 0; st >>= 1) {
        if (tid < st) { ss[tid] += ss[tid + st]; sq[tid] += sq[tid + st]; }
        __syncthreads();
    }
    if (tid == 0) {
        double cnt = (double)tot;
        double mean = ss[0] / cnt;
        double var = fmax(sq[0] / cnt - mean * mean, 0.0);
        gst[blk * 2]     = mean;
        gst[blk * 2 + 1] = rsqrt(var + 1e-5);
    }
}

// ---------------- GroupNorm apply (+relu/lrelu), in place ----------------
__global__ void k_gn_apply(float* __restrict__ h, int C, int cg, const double* __restrict__ gst,
                           const float* __restrict__ g, const float* __restrict__ bb, int act) {
    int i = blockIdx.x * blockDim.x + threadIdx.x;   // M*C
    int m = i / C, c = i % C;
    int b = m >> 11, grp = c / cg;
    double mean = gst[(b * 32 + grp) * 2], inv = gst[(b * 32 + grp) * 2 + 1];
    double v = ((double)h[i] - mean) * inv * (double)g[c] + (double)bb[c];
    v = act ? fmax(v, 0.0) : ((v >= 0.0) ? v : 0.2 * v);
    h[i] = (float)v;
}

// ---------------- final GN + relu + transpose to [B,128,N] ----------------
__global__ void k_gn_out(const float* __restrict__ h, const double* __restrict__ gst,
                         const float* __restrict__ g, const float* __restrict__ bb,
                         float* __restrict__ out) {
    int i = blockIdx.x * blockDim.x + threadIdx.x;   // B*128*N
    int b = i / (128 * NPTS); int r = i % (128 * NPTS); int c = r / NPTS; int n = r % NPTS;
    int grp = c >> 2;
    double mean = gst[(b * 32 + grp) * 2], inv = gst[(b * 32 + grp) * 2 + 1];
    double v = ((double)h[((size_t)b * NPTS + n) * 128 + c] - mean) * inv * (double)g[c] + (double)bb[c];
    out[i] = (float)fmax(v, 0.0);
}

// ---------------- global pooling: grid (16, 8), 256 thr ----------------
__global__ void k_glb(const float* __restrict__ h, double* __restrict__ glb) {
    __shared__ double smx[256], ssm[256];
    int b  = blockIdx.y;
    int c  = blockIdx.x * 32 + (threadIdx.x & 31);
    int g  = threadIdx.x >> 5;
    const float* hb = h + (size_t)b * NPTS * 512;
    double mx = NEG_INF_D, s = 0.0;
    for (int n = g; n < NPTS; n += 8) {
        double v = (double)hb[(size_t)n * 512 + c];
        mx = fmax(mx, v); s += v;
    }
    smx[threadIdx.x] = mx; ssm[threadIdx.x] = s;
    __syncthreads();
    for (int st = 128; st >= 32; st >>= 1) {
        if (threadIdx.x < st) {
            smx[threadIdx.x] = fmax(smx[threadIdx.x], smx[threadIdx.x + st]);
            ssm[threadIdx.x] += ssm[threadIdx.x + st];
        }
        __syncthreads();
    }
    if (threadIdx.x < 32) {
        glb[b * 1024 + c]       = smx[threadIdx.x];
        glb[b * 1024 + 512 + c] = ssm[threadIdx.x] * (1.0 / NPTS);
    }
}

// ---------------- v[b,o] = bm1[o] + glb[b,:] . wm1[o,512:1536] ----------------
__global__ void k_vvec(const double* __restrict__ glb, const float* __restrict__ wm1,
                       const float* __restrict__ bm1, double* __restrict__ v) {
    int b = blockIdx.x; int o = threadIdx.x;
    const double* gb = glb + b * 1024;
    const float*  wr = wm1 + (size_t)o * 1536 + 512;
    double s = (double)bm1[o];
    for (int c = 0; c < 1024; ++c) s += gb[c] * (double)wr[c];
    v[b * 512 + o] = s;
}

// =================================================================================
extern "C" void kernel_launch(void* const* d_in, const int* in_sizes, int n_in,
                              void* d_out, int out_size, void* d_ws, size_t ws_size,
                              hipStream_t stream) {
    const float* xyz = (const float*)d_in[0];
    const float* w1 = (const float*)d_in[1];  const float* g1 = (const float*)d_in[2];  const float* b1 = (const float*)d_in[3];
    const float* w2 = (const float*)d_in[4];  const float* g2 = (const float*)d_in[5];  const float* b2 = (const float*)d_in[6];
    const float* w3 = (const float*)d_in[7];  const float* g3 = (const float*)d_in[8];  const float* b3 = (const float*)d_in[9];
    const float* w4 = (const float*)d_in[10]; const float* g4 = (const float*)d_in[11]; const float* b4 = (const float*)d_in[12];
    const float* w5 = (const float*)d_in[13]; const float* g5 = (const float*)d_in[14]; const float* b5 = (const float*)d_in[15];
    const float* wm1 = (const float*)d_in[16]; const float* bm1 = (const float*)d_in[17];
    const float* g6 = (const float*)d_in[18]; const float* b6 = (const float*)d_in[19];
    const float* wm2 = (const float*)d_in[20]; const float* bm2 = (const float*)d_in[21];
    const float* g7 = (const float*)d_in[22]; const float* b7 = (const float*)d_in[23];
    const float* wm3 = (const float*)d_in[24]; const float* bm3 = (const float*)d_in[25];
    const float* g8 = (const float*)d_in[26]; const float* b8 = (const float*)d_in[27];

    char* ws = (char*)d_ws;
    const size_t MiB = 1024ull * 1024;
    const size_t oLoc  = 0;                      // loc f32 [16384,512] 32 MiB
    const size_t oU    = 32 * MiB;               // union region (48 MiB)
    const size_t oPd   = oU;                     //   pd f32 [2048,2048] 16 MiB       (knn)
    const size_t oZu4  = oU;                     //   zu4 f32 [4][2048,512] 16 MiB    (conv4; pd dead)
    const size_t oPart = oU + 16 * MiB;          //   part f64 <=4 MiB                (conv)
    const size_t oYmax = oU + 20 * MiB;          //   ymax f32 [16384,<=256] 16 MiB   (conv)
    const size_t oH5   = oU;                     //   h5/h6/h8 f32 [16384,512] 32 MiB (dense)
    const size_t oH7   = oU + 32 * MiB;          //   h7 f32 [16384,256] 16 MiB       (dense)
    const size_t oX0   = 80 * MiB;               // x0 f32 [16384,4]
    const size_t oXX   = oX0 + 256 * 1024;       // xx f32 [16384]
    const size_t oIdx  = oXX + 64 * 1024;        // idx [16384,20] int
    const size_t oMst  = oIdx + 1344 * 1024;
    const size_t oVst  = oMst + 1024;
    const size_t oGst  = oVst + 1024;            // gst f64 [512]
    const size_t oGlb  = oGst + 4096;            // glb f64 [8,1024]
    const size_t oVv   = oGlb + 65536;           // vv f64 [8,512]
    const size_t oW2   = oVv + 32768;            // w2p f32 [512,128]

    float*  loc  = (float*)(ws + oLoc);
    float*  pd   = (float*)(ws + oPd);
    float*  zu4  = (float*)(ws + oZu4);
    double* part = (double*)(ws + oPart);
    float*  ymax = (float*)(ws + oYmax);
    float*  h5   = (float*)(ws + oH5);
    float*  h7   = (float*)(ws + oH7);
    float*  x0   = (float*)(ws + oX0);
    float*  xx   = (float*)(ws + oXX);
    int*    idx  = (int*)  (ws + oIdx);
    float*  mst  = (float*)(ws + oMst);
    float*  vst  = (float*)(ws + oVst);
    double* gst  = (double*)(ws + oGst);
    double* glb  = (double*)(ws + oGlb);
    double* vv   = (double*)(ws + oVv);
    float*  w2p  = (float*)(ws + oW2);

    dim3 t16(16, 16);
    const int M = BATCH * NPTS;   // 16384

    k_transpose_in<<<(BATCH*3*NPTS + 255)/256, 256, 0, stream>>>(xyz, x0);

    // ---- layers 1-3: faithful knn + ROUND-7 frozen conv/stats ----
    struct EB { int isX0; int ldx; int coff; int C; int O; const float* w; const float* g; const float* bb; int coff_out; };
    EB eb[3] = {
        { 1, 4,   0,  3,  64,  w1, g1, b1, 0   },
        { 0, 512, 0,  64, 64,  w2, g2, b2, 64  },
        { 0, 512, 64, 64, 128, w3, g3, b3, 128 },
    };
    for (int e = 0; e < 3; ++e) {
        const EB& p = eb[e];
        const float* X = p.isX0 ? x0 : loc;
        k_sumsq<<<M/256, 256, 0, stream>>>(X, p.ldx, p.coff, p.C, xx);
        for (int b = 0; b < BATCH; ++b) {
            k_pd<<<dim3(NPTS/64, NPTS/64), t16, 0, stream>>>(X + (size_t)b*NPTS*p.ldx, p.ldx, p.coff, p.C,
                                                             xx + (size_t)b*NPTS, pd);
            k_topk<<<NPTS/4, 256, 0, stream>>>(pd, b * NPTS, idx);
        }
        k_edge_conv<<<M/8, p.O, 0, stream>>>(X, p.ldx, p.coff, p.C, p.O, p.w, idx, ymax, part);
        k_bn_stats<<<1, p.O, 0, stream>>>(part, M/8, p.O, mst, vst);
        k_bn_apply<<<(M*p.O)/256, 256, 0, stream>>>(ymax, p.O, mst, vst, p.g, p.bb, loc, p.coff_out);
    }

    // ---- layer 4: faithful knn + factored conv (value path), z-batched by half-batch ----
    k_sumsq<<<M/256, 256, 0, stream>>>(loc, 512, 128, 128, xx);
    for (int b = 0; b < BATCH; ++b) {
        k_pd<<<dim3(NPTS/64, NPTS/64), t16, 0, stream>>>(loc + (size_t)b*NPTS*512, 512, 128, 128,
                                                         xx + (size_t)b*NPTS, pd);
        k_topk<<<NPTS/4, 256, 0, stream>>>(pd, b * NPTS, idx);
    }
    // idx complete for all batches -> pd region dead -> zu4 may overwrite it
    k_wprep<<<(512*128 + 255)/256, 256, 0, stream>>>(w4, 128, 256, w2p);
    for (int hb = 0; hb < 2; ++hb) {
        int b0 = hb * 4;
        k_gemm_t<<<dim3(512/128, NPTS/128, 4), t16, 0, stream>>>(
            loc + (size_t)b0*NPTS*512, 512, 128, w2p, 128, zu4, 512, 128,
            nullptr, nullptr, 0, (size_t)NPTS*512, (size_t)NPTS*512);
        k_edge_reduce4<<<dim3(128, 4), 256, 0, stream>>>(zu4, idx, ymax, part, b0);
    }
    k_bn_stats4<<<256, 256, 0, stream>>>(part, BATCH*128, mst, vst);
    k_bn_apply<<<(M*256)/256, 256, 0, stream>>>(ymax, 256, mst, vst, g4, b4, loc, 256);

    // ---- dense phase ----
    float* h6 = h5;              // h5 dead after glb
    float* h8 = h5;              // h6 dead after wm2

    k_gemm_t<<<dim3(512/128, M/128), t16, 0, stream>>>(loc, 512, 0, w5, 512, h5, 512, 512,
                                                       nullptr, nullptr, 0, 0, 0);
    k_gn_stats<<<BATCH*32, 256, 0, stream>>>(h5, 512, 16, gst);
    k_gn_apply<<<(M*512)/256, 256, 0, stream>>>(h5, 512, 16, gst, g5, b5, 0);

    k_glb<<<dim3(16, 8), 256, 0, stream>>>(h5, glb);
    k_vvec<<<BATCH, 512, 0, stream>>>(glb, wm1, bm1, vv);

    k_gemm_t<<<dim3(512/128, M/128), t16, 0, stream>>>(loc, 512, 0, wm1, 1536, h6, 512, 512,
                                                       nullptr, vv, 512, 0, 0);
    k_gn_stats<<<BATCH*32, 256, 0, stream>>>(h6, 512, 16, gst);
    k_gn_apply<<<(M*512)/256, 256, 0, stream>>>(h6, 512, 16, gst, g6, b6, 1);

    k_gemm_t<<<dim3(256/128, M/128), t16, 0, stream>>>(h6, 512, 0, wm2, 512, h7, 256, 512,
                                                       bm2, nullptr, 0, 0, 0);
    k_gn_stats<<<BATCH*32, 256, 0, stream>>>(h7, 256, 8, gst);
    k_gn_apply<<<(M*256)/256, 256, 0, stream>>>(h7, 256, 8, gst, g7, b7, 1);

    k_gemm_t<<<dim3(128/128, M/128), t16, 0, stream>>>(h7, 256, 0, wm3, 256, h8, 128, 256,
                                                       bm3, nullptr, 0, 0, 0);
    k_gn_stats<<<BATCH*32, 256, 0, stream>>>(h8, 128, 4, gst);
    k_gn_out<<<(BATCH*128*NPTS)/256, 256, 0, stream>>>(h8, gst, g8, b8, (float*)d_out);
}